// Round 3
// baseline (203.955 us; speedup 1.0000x reference)
//
#include <hip/hip_runtime.h>

// TopicRouter: logits = h @ gate_w^T + gate_b ; top-2 ; softmax over top-2.
// Outputs flat in d_out (float32): [0, 2B)   = topk indices as floats
//                                  [2B, 4B)  = softmax weights
//
// Design: wave-per-token. Lane owns d in {g*256 + lane*4 + j : g<3, j<4}
// -> 3 coalesced float4 loads per token per wave. gate_w cached in 96 f32
// VGPRs per lane (loaded once per wave, amortized over the grid-stride
// token loop). Accumulate in f64 (idx threshold 0.14 means a single top-2
// flip vs the f64 numpy ref fails; f32 dot error ~1e-6 vs expected min
// rank2/rank3 gap ~4e-6 over 131072 tokens -> must use f64).

#define B_TOKENS 131072
#define DM 768
#define NE 8

__global__ __launch_bounds__(256) void topic_router_kernel(
    const float* __restrict__ h,     // [B, 768]
    const float* __restrict__ gw,    // [8, 768]
    const float* __restrict__ gb,    // [8]
    float* __restrict__ out)         // [2B idx floats][2B weight floats]
{
    const int lane = threadIdx.x & 63;
    const int wave_global = (blockIdx.x * blockDim.x + threadIdx.x) >> 6;
    const int n_waves = (gridDim.x * blockDim.x) >> 6;

    // Cache gate_w fragments: wf[e][g][j] = gw[e][g*256 + lane*4 + j]
    float wf[NE][3][4];
#pragma unroll
    for (int e = 0; e < NE; ++e)
#pragma unroll
        for (int g = 0; g < 3; ++g) {
            const float4 v = *reinterpret_cast<const float4*>(
                &gw[e * DM + g * 256 + lane * 4]);
            wf[e][g][0] = v.x; wf[e][g][1] = v.y;
            wf[e][g][2] = v.z; wf[e][g][3] = v.w;
        }

    float bias[NE];
#pragma unroll
    for (int e = 0; e < NE; ++e) bias[e] = gb[e];

    for (int t = wave_global; t < B_TOKENS; t += n_waves) {
        const float* hrow = h + (size_t)t * DM;

        double acc[NE] = {0, 0, 0, 0, 0, 0, 0, 0};
#pragma unroll
        for (int g = 0; g < 3; ++g) {
            const float4 hv = *reinterpret_cast<const float4*>(
                &hrow[g * 256 + lane * 4]);
            const double hd0 = (double)hv.x, hd1 = (double)hv.y;
            const double hd2 = (double)hv.z, hd3 = (double)hv.w;
#pragma unroll
            for (int e = 0; e < NE; ++e) {
                acc[e] = fma(hd0, (double)wf[e][g][0], acc[e]);
                acc[e] = fma(hd1, (double)wf[e][g][1], acc[e]);
                acc[e] = fma(hd2, (double)wf[e][g][2], acc[e]);
                acc[e] = fma(hd3, (double)wf[e][g][3], acc[e]);
            }
        }

        // Wave-wide all-reduce (sum) per expert, then add bias.
#pragma unroll
        for (int e = 0; e < NE; ++e) {
            double v = acc[e];
            v += __shfl_xor(v, 1);
            v += __shfl_xor(v, 2);
            v += __shfl_xor(v, 4);
            v += __shfl_xor(v, 8);
            v += __shfl_xor(v, 16);
            v += __shfl_xor(v, 32);
            acc[e] = v + (double)bias[e];
        }

        // Top-2 with lax.top_k tie-break (lower index wins on equality).
        int i0 = 0; double v0 = acc[0];
#pragma unroll
        for (int e = 1; e < NE; ++e)
            if (acc[e] > v0) { v0 = acc[e]; i0 = e; }
        int i1 = (i0 == 0) ? 1 : 0; double v1 = acc[i1];
#pragma unroll
        for (int e = 0; e < NE; ++e)
            if (e != i0 && acc[e] > v1) { v1 = acc[e]; i1 = e; }

        // softmax over [v0, v1] with v0 >= v1
        const float ex = expf((float)(v1 - v0));   // in (0, 1]
        const float w1 = ex / (1.0f + ex);
        const float w0 = 1.0f - w1;

        if (lane == 0) {
            *reinterpret_cast<float2*>(&out[2 * (size_t)t]) =
                make_float2((float)i0, (float)i1);
            *reinterpret_cast<float2*>(&out[2 * (size_t)B_TOKENS + 2 * (size_t)t]) =
                make_float2(w0, w1);
        }
    }
}

extern "C" void kernel_launch(void* const* d_in, const int* in_sizes, int n_in,
                              void* d_out, int out_size, void* d_ws, size_t ws_size,
                              hipStream_t stream) {
    const float* h  = (const float*)d_in[0];
    const float* gw = (const float*)d_in[1];
    const float* gb = (const float*)d_in[2];
    float* out = (float*)d_out;

    dim3 grid(2048), block(256);
    topic_router_kernel<<<grid, block, 0, stream>>>(h, gw, gb, out);
}